// Round 5
// baseline (399.025 us; speedup 1.0000x reference)
//
#include <hip/hip_runtime.h>
#include <hip/hip_bf16.h>
#include <cstdint>
#include <cstddef>

#define SEQLEN 2048
#define NBATCH 2
#define NHEAD  16
#define HDIM   64
#define HID    1024
#define MROWS  4096   // row r = s*2 + b

typedef __bf16 bf16x8 __attribute__((ext_vector_type(8)));
typedef float f32x4 __attribute__((ext_vector_type(4)));
typedef unsigned short ushort8 __attribute__((ext_vector_type(8)));

#define MFMA16(a, b, c) __builtin_amdgcn_mfma_f32_16x16x32_bf16((a), (b), (c), 0, 0, 0)

#define GLOAD_LDS16(g, l)                                                        \
    __builtin_amdgcn_global_load_lds(                                            \
        (const __attribute__((address_space(1))) void*)(g),                      \
        (__attribute__((address_space(3))) void*)(l), 16, 0, 0)

#define SBAR() __builtin_amdgcn_s_barrier()
#define SCHED_FENCE() __builtin_amdgcn_sched_barrier(0)
#define WAIT_VMCNT0() asm volatile("s_waitcnt vmcnt(0)" ::: "memory")
#define WAIT_LGKM0()  asm volatile("s_waitcnt lgkmcnt(0)" ::: "memory")

static __device__ __forceinline__ unsigned int pack_bf16_pair(float lo, float hi) {
    unsigned short a = __builtin_bit_cast(unsigned short, (__bf16)lo);
    unsigned short b = __builtin_bit_cast(unsigned short, (__bf16)hi);
    return ((unsigned int)b << 16) | a;
}

// ---------------------------------------------------------------------------
// conv6: fp32 -> bf16 for {query,key,value,Wq,Wk,Wv} into scratch (attn area)
// ---------------------------------------------------------------------------
__global__ __launch_bounds__(256) void conv6(
    const float* __restrict__ s0, const float* __restrict__ s1, const float* __restrict__ s2,
    const float* __restrict__ s3, const float* __restrict__ s4, const float* __restrict__ s5,
    unsigned short* __restrict__ Sc)
{
    const int y = blockIdx.y;
    const float* src = (y == 0) ? s0 : (y == 1) ? s1 : (y == 2) ? s2
                     : (y == 3) ? s3 : (y == 4) ? s4 : s5;
    const size_t M1 = 1u << 20;
    unsigned short* dst = (y < 3) ? (Sc + (size_t)y * 4 * M1) : (Sc + 12 * M1 + (size_t)(y - 3) * M1);
    const size_t n = (y < 3) ? 4 * M1 : M1;

    const size_t i = ((size_t)blockIdx.x * 256 + threadIdx.x) * 8;
    if (i >= n) return;
    float4 f0 = *(const float4*)(src + i);
    float4 f1 = *(const float4*)(src + i + 4);
    ushort8 o;
    o[0] = __builtin_bit_cast(unsigned short, (__bf16)f0.x);
    o[1] = __builtin_bit_cast(unsigned short, (__bf16)f0.y);
    o[2] = __builtin_bit_cast(unsigned short, (__bf16)f0.z);
    o[3] = __builtin_bit_cast(unsigned short, (__bf16)f0.w);
    o[4] = __builtin_bit_cast(unsigned short, (__bf16)f1.x);
    o[5] = __builtin_bit_cast(unsigned short, (__bf16)f1.y);
    o[6] = __builtin_bit_cast(unsigned short, (__bf16)f1.z);
    o[7] = __builtin_bit_cast(unsigned short, (__bf16)f1.w);
    *(ushort8*)(dst + i) = o;
}

// ---------------------------------------------------------------------------
// m97-style stage: 128 rows x 64 cols bf16 via gload_lds w16, XOR-swizzled.
// ---------------------------------------------------------------------------
#define GEMM_STAGE(LDSBUF, SRCP)                                                  \
    _Pragma("unroll")                                                             \
    for (int c = 0; c < 4; ++c) {                                                 \
        const int rb = (w << 5) + (c << 3);                                       \
        const int row = rb + (lane >> 3);                                         \
        const unsigned short* src = (SRCP) + (size_t)row * HID + k0               \
                                  + (((lane & 7) ^ ((lane >> 3) & 7)) << 3);      \
        GLOAD_LDS16(src, &LDSBUF[rb * 64]);                                       \
    }

// frag read from that layout: row in [0,128), kk in {0,1}
#define FRAG_AT(BUFC, rowv, kkv)                                                  \
    (*(const bf16x8*)((BUFC) + ((rowv) << 7) + ((((kkv) << 6) | (fg << 4)) ^ (((rowv) & 7) << 4))))

// ---------------------------------------------------------------------------
// qkv_gemm: C = X @ W^T + bias -> bf16. Tile 128x128, BK=64 (round-3 proven).
// ---------------------------------------------------------------------------
__global__ __launch_bounds__(256) void qkv_gemm(
    const unsigned short* __restrict__ Sc,
    const float* __restrict__ bq, const float* __restrict__ bk, const float* __restrict__ bv,
    unsigned short* __restrict__ Qb, unsigned short* __restrict__ Kb, unsigned short* __restrict__ Vb)
{
    const int z = blockIdx.z;
    const size_t M1 = 1u << 20;
    const unsigned short* A = Sc + (size_t)z * 4 * M1;
    const unsigned short* B = Sc + 12 * M1 + (size_t)z * M1;
    const float* bias = (z == 0) ? bq : (z == 1) ? bk : bv;
    unsigned short* dst = (z == 0) ? Qb : (z == 1) ? Kb : Vb;

    __shared__ unsigned short As[128 * 64];
    __shared__ unsigned short Bs[128 * 64];

    const int t = threadIdx.x, lane = t & 63, w = t >> 6;
    const int wm = w >> 1, wn = w & 1;
    const int bm = blockIdx.x * 128, bn = blockIdx.y * 128;
    const int fr = lane & 15, fg = lane >> 4;

    f32x4 acc[4][4] = {};
    const char* Ac = (const char*)As;
    const char* Bc = (const char*)Bs;

    for (int k0 = 0; k0 < HID; k0 += 64) {
        __syncthreads();
        GEMM_STAGE(As, A + (size_t)bm * HID)
        GEMM_STAGE(Bs, B + (size_t)bn * HID)
        __syncthreads();

        #pragma unroll
        for (int kk = 0; kk < 2; ++kk) {
            bf16x8 a_h[4], b_h[4];
            #pragma unroll
            for (int m = 0; m < 4; ++m) a_h[m] = FRAG_AT(Ac, wm * 64 + m * 16 + fr, kk);
            #pragma unroll
            for (int n = 0; n < 4; ++n) b_h[n] = FRAG_AT(Bc, wn * 64 + n * 16 + fr, kk);
            __builtin_amdgcn_s_setprio(1);
            #pragma unroll
            for (int m = 0; m < 4; ++m)
                #pragma unroll
                for (int n = 0; n < 4; ++n)
                    acc[m][n] = MFMA16(a_h[m], b_h[n], acc[m][n]);
            __builtin_amdgcn_s_setprio(0);
        }
    }

    #pragma unroll
    for (int n = 0; n < 4; ++n) {
        const int gc = bn + wn * 64 + n * 16 + fr;
        const float bb = bias[gc];
        #pragma unroll
        for (int m = 0; m < 4; ++m)
            #pragma unroll
            for (int r = 0; r < 4; ++r) {
                const int gr = bm + wm * 64 + m * 16 + fg * 4 + r;
                *(__bf16*)&dst[(size_t)gr * HID + gc] = (__bf16)(acc[m][n][r] + bb);
            }
    }
}

// ---------------------------------------------------------------------------
// vtrans: LDS-tiled transpose Vb [s2][h*64+d] -> Vt [b][h][d][s]
// ---------------------------------------------------------------------------
__global__ __launch_bounds__(256) void vtrans(
    const unsigned short* __restrict__ Vb, unsigned short* __restrict__ Vt)
{
    __shared__ unsigned short T[64][66];
    const int t = threadIdx.x;
    const int s0 = blockIdx.x * 64, h = blockIdx.y, b = blockIdx.z;

    {
        const int s_l = t >> 2, d0 = (t & 3) * 16;
        const unsigned short* src = Vb + (((size_t)(s0 + s_l) * 2 + b) << 10) + (h << 6) + d0;
        *(ushort8*)&T[s_l][d0]     = *(const ushort8*)src;
        *(ushort8*)&T[s_l][d0 + 8] = *(const ushort8*)(src + 8);
    }
    __syncthreads();
    {
        const int d_l = t >> 2, sc = (t & 3) * 16;
        ushort8 o0, o1;
        #pragma unroll
        for (int j = 0; j < 8; ++j) { o0[j] = T[sc + j][d_l]; o1[j] = T[sc + 8 + j][d_l]; }
        unsigned short* dst = Vt + (((size_t)((b << 4) + h) * 64 + d_l) << 11) + s0 + sc;
        *(ushort8*)dst       = o0;
        *(ushort8*)(dst + 8) = o1;
    }
}

// ---------------------------------------------------------------------------
// attn2: swapped-QK^T fused attention; 2-phase pipeline with correct vmcnt:
// per kt {STAGE(kt+1) issued first; compute; vmcnt(0); s_barrier}.
// Lane (fr,fg): q=fr, k=16n+fg*4+r. LDS 48 KB -> 3 blocks/CU.
// ---------------------------------------------------------------------------
#define STAGE_K(ktv, bufsel)                                                     \
    {                                                                            \
        const int kti_ = (ktv) & 15;                                             \
        _Pragma("unroll")                                                        \
        for (int c_ = 0; c_ < 4; ++c_) {                                         \
            const int rb_ = (w << 5) + (c_ << 3);                                \
            const int rl_ = rb_ + (lane >> 3);                                   \
            const unsigned short* ks_ = Kb + (((size_t)((kti_ << 7) + rl_) * 2 + b) << 10) \
                + (h << 6) + (((lane & 7) ^ (rl_ & 7)) << 3);                    \
            GLOAD_LDS16(ks_, &Ks[bufsel][rb_ * 64]);                             \
        }                                                                        \
    }

__global__ __launch_bounds__(256) void attn2(
    const unsigned short* __restrict__ Qb, const unsigned short* __restrict__ Kb,
    const unsigned short* __restrict__ Vt, float* __restrict__ attn_out,
    unsigned short* __restrict__ Hb)
{
    __shared__ unsigned short Ks[2][128 * 64];   // 32 KB double-buffered K
    __shared__ unsigned short Pl[4][16 * 128];   // 16 KB, per-wave 16x128 bf16

    const int flat = blockIdx.x + (blockIdx.y << 4) + (blockIdx.z << 8);
    const int nf = (flat & 7) * 64 + (flat >> 3);
    const int qblk = nf & 15, h = (nf >> 4) & 15, b = nf >> 8;

    const int t = threadIdx.x, lane = t & 63, w = t >> 6;
    const int fr = lane & 15, fg = lane >> 4;
    const int fg4 = fg << 2, fg16 = fg << 4;
    const int qbase = qblk * 128 + w * 32;
    const float c_exp = 0.18033688011112042f;    // log2(e)/8

    bf16x8 qf[2][2];
    #pragma unroll
    for (int mi = 0; mi < 2; ++mi) {
        const int q = qbase + mi * 16 + fr;
        const unsigned short* qp = Qb + (((size_t)q * 2 + b) << 10) + (h << 6);
        qf[mi][0] = *(const bf16x8*)(qp + (fg << 3));
        qf[mi][1] = *(const bf16x8*)(qp + 32 + (fg << 3));
    }

    char* Plc = (char*)&Pl[w][0];
    float lsum[2] = {0.f, 0.f};

    // ---------------- pass 1: row sums ----------------
    STAGE_K(0, 0);
    WAIT_VMCNT0();
    SBAR();
    for (int kt = 0; kt < 16; ++kt) {
        STAGE_K(kt + 1, (kt + 1) & 1);           // issue early; consumed next iter

        const char* Kc = (const char*)Ks[kt & 1];
        f32x4 s_[2][8] = {};
        __builtin_amdgcn_s_setprio(1);
        #pragma unroll
        for (int n = 0; n < 8; ++n) {
            const int row = (n << 4) + fr;
            const int rx = (row & 7) << 4;
            #pragma unroll
            for (int kk = 0; kk < 2; ++kk) {
                bf16x8 kf = *(const bf16x8*)(Kc + (row << 7) + (((kk << 6) | fg16) ^ rx));
                s_[0][n] = MFMA16(kf, qf[0][kk], s_[0][n]);
                s_[1][n] = MFMA16(kf, qf[1][kk], s_[1][n]);
            }
        }
        __builtin_amdgcn_s_setprio(0);

        #pragma unroll
        for (int mi = 0; mi < 2; ++mi) {
            float a = 0.f;
            #pragma unroll
            for (int n = 0; n < 8; ++n)
                #pragma unroll
                for (int r = 0; r < 4; ++r)
                    a += exp2f(s_[mi][n][r] * c_exp);
            lsum[mi] += a;
        }

        WAIT_VMCNT0();
        SBAR();
    }

    float li[2];
    #pragma unroll
    for (int mi = 0; mi < 2; ++mi) {
        float v = lsum[mi];
        v += __shfl_xor(v, 16);
        v += __shfl_xor(v, 32);
        li[mi] = -__log2f(v);                    // fold 1/sum into exponent
    }

    f32x4 oacc[2][4] = {};
    float* attnB = attn_out + ((size_t)((b << 4) + h) << 22);
    const size_t vhead = (size_t)((b << 4) + h) << 6;

    // ---------------- pass 2 ----------------
    // pass 1's final STAGE_K staged tile 0 into Ks[0]; drained by final vmcnt(0).
    for (int kt = 0; kt < 16; ++kt) {
        STAGE_K(kt + 1, (kt + 1) & 1);

        const char* Kc = (const char*)Ks[kt & 1];
        f32x4 s_[2][8] = {};
        __builtin_amdgcn_s_setprio(1);
        #pragma unroll
        for (int n = 0; n < 8; ++n) {
            const int row = (n << 4) + fr;
            const int rx = (row & 7) << 4;
            #pragma unroll
            for (int kk = 0; kk < 2; ++kk) {
                bf16x8 kf = *(const bf16x8*)(Kc + (row << 7) + (((kk << 6) | fg16) ^ rx));
                s_[0][n] = MFMA16(kf, qf[0][kk], s_[0][n]);
                s_[1][n] = MFMA16(kf, qf[1][kk], s_[1][n]);
            }
        }
        __builtin_amdgcn_s_setprio(0);

        const int rxl = (fr & 7) << 4;
        #pragma unroll
        for (int mi = 0; mi < 2; ++mi) {
            // p = 2^(s*c + log2(inv)); plain f32x4 store; packed b64 -> Pl
            float* ab = attnB + ((size_t)(qbase + (mi << 4) + fr) << 11) + (kt << 7) + fg4;
            #pragma unroll
            for (int n = 0; n < 8; ++n) {
                f32x4 p;
                #pragma unroll
                for (int r = 0; r < 4; ++r)
                    p[r] = exp2f(__builtin_fmaf(s_[mi][n][r], c_exp, li[mi]));
                *(f32x4*)(ab + (n << 4)) = p;
                uint2 pk;
                pk.x = pack_bf16_pair(p[0], p[1]);
                pk.y = pack_bf16_pair(p[2], p[3]);
                *(uint2*)(Plc + (fr << 8) + (((n << 5) | (fg << 3)) ^ rxl)) = pk;
            }
            WAIT_LGKM0();
            SCHED_FENCE();                        // rule #18: pin MFMA after wait

            // PV (this mi): oacc[mi] += P(16x128) @ V(128x64)
            __builtin_amdgcn_s_setprio(1);
            #pragma unroll
            for (int kk2 = 0; kk2 < 4; ++kk2) {
                bf16x8 pa = *(const bf16x8*)(Plc + (fr << 8) + (((kk2 << 6) | fg16) ^ rxl));
                #pragma unroll
                for (int n2 = 0; n2 < 4; ++n2) {
                    bf16x8 vf = *(const bf16x8*)(Vt + ((vhead + (n2 << 4) + fr) << 11)
                                                 + (kt << 7) + (kk2 << 5) + (fg << 3));
                    oacc[mi][n2] = MFMA16(pa, vf, oacc[mi][n2]);
                }
            }
            __builtin_amdgcn_s_setprio(0);
        }

        WAIT_VMCNT0();
        SBAR();
    }

    #pragma unroll
    for (int mi = 0; mi < 2; ++mi)
        #pragma unroll
        for (int n2 = 0; n2 < 4; ++n2)
            #pragma unroll
            for (int r = 0; r < 4; ++r) {
                const int q = qbase + (mi << 4) + fg4 + r;
                *(__bf16*)&Hb[(((size_t)q * 2 + b) << 10) + (h << 6) + (n2 << 4) + fr] =
                    (__bf16)oacc[mi][n2][r];
            }
}

// ---------------------------------------------------------------------------
// out_proj: out = H @ Wo^T + bo (fp32). A: bf16 Hb via gload_lds.
// B: Wo fp32 -> convert in-register -> swizzled ds_write (no wconv kernel).
// ---------------------------------------------------------------------------
__global__ __launch_bounds__(256) void out_proj(
    const unsigned short* __restrict__ Hb, const float* __restrict__ Wo,
    const float* __restrict__ bo, float* __restrict__ out)
{
    __shared__ unsigned short As[128 * 64];
    __shared__ unsigned short Bs[128 * 64];

    const int t = threadIdx.x, lane = t & 63, w = t >> 6;
    const int wm = w >> 1, wn = w & 1;
    const int bm = blockIdx.x * 128, bn = blockIdx.y * 128;
    const int fr = lane & 15, fg = lane >> 4;

    f32x4 acc[4][4] = {};
    const char* Ac = (const char*)As;
    const char* Bc = (const char*)Bs;
    char* Bw = (char*)Bs;

    const int brow = t >> 1, bhalf = t & 1;     // B-stage mapping

    for (int k0 = 0; k0 < HID; k0 += 64) {
        __syncthreads();
        GEMM_STAGE(As, Hb + (size_t)bm * HID)
        {
            // B tile: rows bn+brow, cols k0 + bhalf*32 .. +32 (fp32 -> bf16)
            const float* src = Wo + (size_t)(bn + brow) * HID + k0 + bhalf * 32;
            #pragma unroll
            for (int c = 0; c < 4; ++c) {
                float4 f0 = *(const float4*)(src + c * 8);
                float4 f1 = *(const float4*)(src + c * 8 + 4);
                ushort8 o;
                o[0] = __builtin_bit_cast(unsigned short, (__bf16)f0.x);
                o[1] = __builtin_bit_cast(unsigned short, (__bf16)f0.y);
                o[2] = __builtin_bit_cast(unsigned short, (__bf16)f0.z);
                o[3] = __builtin_bit_cast(unsigned short, (__bf16)f0.w);
                o[4] = __builtin_bit_cast(unsigned short, (__bf16)f1.x);
                o[5] = __builtin_bit_cast(unsigned short, (__bf16)f1.y);
                o[6] = __builtin_bit_cast(unsigned short, (__bf16)f1.z);
                o[7] = __builtin_bit_cast(unsigned short, (__bf16)f1.w);
                const int cslot = bhalf * 4 + c;
                *(ushort8*)(Bw + (brow << 7) + ((cslot << 4) ^ ((brow & 7) << 4))) = o;
            }
        }
        __syncthreads();

        #pragma unroll
        for (int kk = 0; kk < 2; ++kk) {
            bf16x8 a_h[4], b_h[4];
            #pragma unroll
            for (int m = 0; m < 4; ++m) a_h[m] = FRAG_AT(Ac, wm * 64 + m * 16 + fr, kk);
            #pragma unroll
            for (int n = 0; n < 4; ++n) b_h[n] = FRAG_AT(Bc, wn * 64 + n * 16 + fr, kk);
            __builtin_amdgcn_s_setprio(1);
            #pragma unroll
            for (int m = 0; m < 4; ++m)
                #pragma unroll
                for (int n = 0; n < 4; ++n)
                    acc[m][n] = MFMA16(a_h[m], b_h[n], acc[m][n]);
            __builtin_amdgcn_s_setprio(0);
        }
    }

    #pragma unroll
    for (int n = 0; n < 4; ++n) {
        const int gc = bn + wn * 64 + n * 16 + fr;
        const float bb = bo[gc];
        #pragma unroll
        for (int m = 0; m < 4; ++m)
            #pragma unroll
            for (int r = 0; r < 4; ++r) {
                const int gr = bm + wm * 64 + m * 16 + fg * 4 + r;
                out[(size_t)gr * HID + gc] = acc[m][n][r] + bb;
            }
    }
}

// ---------------------------------------------------------------------------
extern "C" void kernel_launch(void* const* d_in, const int* in_sizes, int n_in,
                              void* d_out, int out_size, void* d_ws, size_t ws_size,
                              hipStream_t stream)
{
    (void)in_sizes; (void)n_in; (void)out_size;

    const float* query = (const float*)d_in[0];
    const float* key   = (const float*)d_in[1];
    const float* value = (const float*)d_in[2];
    const float* bq    = (const float*)d_in[4];
    const float* bk    = (const float*)d_in[6];
    const float* bv    = (const float*)d_in[8];
    const float* Wo    = (const float*)d_in[9];
    const float* bo    = (const float*)d_in[10];

    float* out0 = (float*)d_out;
    float* attn = out0 + (size_t)MROWS * HID;

    if (ws_size < (size_t)32 * 1024 * 1024) return;
    const size_t nbuf = (size_t)MROWS * HID;            // 4M bf16 = 8MB
    unsigned short* Qb = (unsigned short*)d_ws;         // [0, 8MB)
    unsigned short* Kb = Qb + nbuf;                     // [8, 16MB)
    unsigned short* Vb = Kb + nbuf;                     // [16, 24MB) -> Hb after vtrans
    unsigned short* Vt = Vb + nbuf;                     // [24, 32MB)
    unsigned short* Hb = Vb;

    unsigned short* Sc = (unsigned short*)attn;         // scratch inside attn area (26MB)

    conv6<<<dim3(2048, 6), 256, 0, stream>>>(query, key, value,
                                             (const float*)d_in[3], (const float*)d_in[5],
                                             (const float*)d_in[7], Sc);
    qkv_gemm<<<dim3(32, 8, 3), 256, 0, stream>>>(Sc, bq, bk, bv, Qb, Kb, Vb);
    vtrans<<<dim3(32, NHEAD, NBATCH), 256, 0, stream>>>(Vb, Vt);
    attn2<<<dim3(16, NHEAD, NBATCH), 256, 0, stream>>>(Qb, Kb, Vt, attn, Hb);
    out_proj<<<dim3(32, 8), 256, 0, stream>>>(Hb, Wo, bo, out0);
}

// Round 6
// 384.811 us; speedup vs baseline: 1.0369x; 1.0369x over previous
//
#include <hip/hip_runtime.h>
#include <hip/hip_bf16.h>
#include <cstdint>
#include <cstddef>

#define SEQLEN 2048
#define NBATCH 2
#define NHEAD  16
#define HDIM   64
#define HID    1024
#define MROWS  4096   // row r = s*2 + b

typedef __bf16 bf16x8 __attribute__((ext_vector_type(8)));
typedef float f32x4 __attribute__((ext_vector_type(4)));
typedef unsigned short ushort8 __attribute__((ext_vector_type(8)));

#define MFMA16(a, b, c) __builtin_amdgcn_mfma_f32_16x16x32_bf16((a), (b), (c), 0, 0, 0)

#define GLOAD_LDS16(g, l)                                                        \
    __builtin_amdgcn_global_load_lds(                                            \
        (const __attribute__((address_space(1))) void*)(g),                      \
        (__attribute__((address_space(3))) void*)(l), 16, 0, 0)

#define SBAR() __builtin_amdgcn_s_barrier()
#define SCHED_FENCE() __builtin_amdgcn_sched_barrier(0)
#define WAIT_VMCNT(n) asm volatile("s_waitcnt vmcnt(" #n ")" ::: "memory")
#define WAIT_LGKM0()  asm volatile("s_waitcnt lgkmcnt(0)" ::: "memory")

static __device__ __forceinline__ unsigned int pack_bf16_pair(float lo, float hi) {
    unsigned short a = __builtin_bit_cast(unsigned short, (__bf16)lo);
    unsigned short b = __builtin_bit_cast(unsigned short, (__bf16)hi);
    return ((unsigned int)b << 16) | a;
}

// ---------------------------------------------------------------------------
// conv6: fp32 -> bf16 for {query,key,value,Wq,Wk,Wv} into scratch (attn area)
// ---------------------------------------------------------------------------
__global__ __launch_bounds__(256) void conv6(
    const float* __restrict__ s0, const float* __restrict__ s1, const float* __restrict__ s2,
    const float* __restrict__ s3, const float* __restrict__ s4, const float* __restrict__ s5,
    unsigned short* __restrict__ Sc)
{
    const int y = blockIdx.y;
    const float* src = (y == 0) ? s0 : (y == 1) ? s1 : (y == 2) ? s2
                     : (y == 3) ? s3 : (y == 4) ? s4 : s5;
    const size_t M1 = 1u << 20;
    unsigned short* dst = (y < 3) ? (Sc + (size_t)y * 4 * M1) : (Sc + 12 * M1 + (size_t)(y - 3) * M1);
    const size_t n = (y < 3) ? 4 * M1 : M1;

    const size_t i = ((size_t)blockIdx.x * 256 + threadIdx.x) * 8;
    if (i >= n) return;
    float4 f0 = *(const float4*)(src + i);
    float4 f1 = *(const float4*)(src + i + 4);
    ushort8 o;
    o[0] = __builtin_bit_cast(unsigned short, (__bf16)f0.x);
    o[1] = __builtin_bit_cast(unsigned short, (__bf16)f0.y);
    o[2] = __builtin_bit_cast(unsigned short, (__bf16)f0.z);
    o[3] = __builtin_bit_cast(unsigned short, (__bf16)f0.w);
    o[4] = __builtin_bit_cast(unsigned short, (__bf16)f1.x);
    o[5] = __builtin_bit_cast(unsigned short, (__bf16)f1.y);
    o[6] = __builtin_bit_cast(unsigned short, (__bf16)f1.z);
    o[7] = __builtin_bit_cast(unsigned short, (__bf16)f1.w);
    *(ushort8*)(dst + i) = o;
}

__global__ __launch_bounds__(256) void wconv(
    const float* __restrict__ Wo, unsigned short* __restrict__ Wob)
{
    const size_t i = ((size_t)blockIdx.x * 256 + threadIdx.x) * 8;
    float4 f0 = *(const float4*)(Wo + i);
    float4 f1 = *(const float4*)(Wo + i + 4);
    ushort8 o;
    o[0] = __builtin_bit_cast(unsigned short, (__bf16)f0.x);
    o[1] = __builtin_bit_cast(unsigned short, (__bf16)f0.y);
    o[2] = __builtin_bit_cast(unsigned short, (__bf16)f0.z);
    o[3] = __builtin_bit_cast(unsigned short, (__bf16)f0.w);
    o[4] = __builtin_bit_cast(unsigned short, (__bf16)f1.x);
    o[5] = __builtin_bit_cast(unsigned short, (__bf16)f1.y);
    o[6] = __builtin_bit_cast(unsigned short, (__bf16)f1.z);
    o[7] = __builtin_bit_cast(unsigned short, (__bf16)f1.w);
    *(ushort8*)(Wob + i) = o;
}

// ---------------------------------------------------------------------------
// Double-buffered bf16 GEMM (BK=32), ONE barrier/iter:
// {stage(it+1); fence; compute(it); vmcnt(0); sbar}. 4 VMEM loads per iter.
// ---------------------------------------------------------------------------
#define GSTAGE32(DSTARR, SRCP, k0v)                                              \
    _Pragma("unroll")                                                            \
    for (int c_ = 0; c_ < 2; ++c_) {                                             \
        const int row_ = (c_ << 6) + (threadIdx.x >> 2);                         \
        const unsigned short* gs_ = (SRCP) + (size_t)row_ * HID + (k0v)          \
            + ((((int)threadIdx.x & 3) ^ ((row_ >> 1) & 3)) << 3);               \
        GLOAD_LDS16(gs_, &(DSTARR)[((c_ << 6) + (((int)threadIdx.x >> 6) << 4)) * 32]); \
    }

#define GEMM_BODY(ApT, BpT)                                                      \
    GSTAGE32(As[0], ApT, 0);                                                     \
    GSTAGE32(Bs[0], BpT, 0);                                                     \
    WAIT_VMCNT(0);                                                               \
    SBAR();                                                                      \
    for (int it = 0; it < 32; ++it) {                                            \
        const int k1 = ((it + 1) & 31) << 5;                                     \
        GSTAGE32(As[(it + 1) & 1], ApT, k1);                                     \
        GSTAGE32(Bs[(it + 1) & 1], BpT, k1);                                     \
        SCHED_FENCE();                                                           \
        const char* Ac = (const char*)As[it & 1];                                \
        const char* Bc = (const char*)Bs[it & 1];                                \
        bf16x8 a_h[4], b_h[4];                                                   \
        _Pragma("unroll")                                                        \
        for (int m = 0; m < 4; ++m) {                                            \
            const int row = wm * 64 + m * 16 + fr;                               \
            a_h[m] = *(const bf16x8*)(Ac + (row << 6) + ((fg ^ ((row >> 1) & 3)) << 4)); \
        }                                                                        \
        _Pragma("unroll")                                                        \
        for (int n = 0; n < 4; ++n) {                                            \
            const int row = wn * 64 + n * 16 + fr;                               \
            b_h[n] = *(const bf16x8*)(Bc + (row << 6) + ((fg ^ ((row >> 1) & 3)) << 4)); \
        }                                                                        \
        __builtin_amdgcn_s_setprio(1);                                           \
        _Pragma("unroll")                                                        \
        for (int m = 0; m < 4; ++m)                                              \
            _Pragma("unroll")                                                    \
            for (int n = 0; n < 4; ++n)                                          \
                acc[m][n] = MFMA16(a_h[m], b_h[n], acc[m][n]);                   \
        __builtin_amdgcn_s_setprio(0);                                           \
        WAIT_VMCNT(0);                                                           \
        SBAR();                                                                  \
    }

__global__ __launch_bounds__(256) void qkv_gemm(
    const unsigned short* __restrict__ Sc,
    const float* __restrict__ bq, const float* __restrict__ bk, const float* __restrict__ bv,
    unsigned short* __restrict__ Qb, unsigned short* __restrict__ Kb, unsigned short* __restrict__ Vb)
{
    const int z = blockIdx.z;
    const size_t M1 = 1u << 20;
    const unsigned short* A = Sc + (size_t)z * 4 * M1;
    const unsigned short* B = Sc + 12 * M1 + (size_t)z * M1;
    const float* bias = (z == 0) ? bq : (z == 1) ? bk : bv;
    unsigned short* dst = (z == 0) ? Qb : (z == 1) ? Kb : Vb;

    __shared__ unsigned short As[2][128 * 32];
    __shared__ unsigned short Bs[2][128 * 32];

    const int t = threadIdx.x, lane = t & 63, w = t >> 6;
    const int wm = w >> 1, wn = w & 1;
    const int bm = blockIdx.x * 128, bn = blockIdx.y * 128;
    const int fr = lane & 15, fg = lane >> 4;

    const unsigned short* Ap = A + (size_t)bm * HID;
    const unsigned short* Bp = B + (size_t)bn * HID;

    f32x4 acc[4][4] = {};
    GEMM_BODY(Ap, Bp)

    #pragma unroll
    for (int n = 0; n < 4; ++n) {
        const int gc = bn + wn * 64 + n * 16 + fr;
        const float bb = bias[gc];
        #pragma unroll
        for (int m = 0; m < 4; ++m)
            #pragma unroll
            for (int r = 0; r < 4; ++r) {
                const int gr = bm + wm * 64 + m * 16 + fg * 4 + r;
                *(__bf16*)&dst[(size_t)gr * HID + gc] = (__bf16)(acc[m][n][r] + bb);
            }
    }
}

// ---------------------------------------------------------------------------
// vtrans: LDS-tiled transpose Vb [s2][h*64+d] -> Vt [b][h][d][s]
// ---------------------------------------------------------------------------
__global__ __launch_bounds__(256) void vtrans(
    const unsigned short* __restrict__ Vb, unsigned short* __restrict__ Vt)
{
    __shared__ unsigned short T[64][66];
    const int t = threadIdx.x;
    const int s0 = blockIdx.x * 64, h = blockIdx.y, b = blockIdx.z;

    {
        const int s_l = t >> 2, d0 = (t & 3) * 16;
        const unsigned short* src = Vb + (((size_t)(s0 + s_l) * 2 + b) << 10) + (h << 6) + d0;
        *(ushort8*)&T[s_l][d0]     = *(const ushort8*)src;
        *(ushort8*)&T[s_l][d0 + 8] = *(const ushort8*)(src + 8);
    }
    __syncthreads();
    {
        const int d_l = t >> 2, sc = (t & 3) * 16;
        ushort8 o0, o1;
        #pragma unroll
        for (int j = 0; j < 8; ++j) { o0[j] = T[sc + j][d_l]; o1[j] = T[sc + 8 + j][d_l]; }
        unsigned short* dst = Vt + (((size_t)((b << 4) + h) * 64 + d_l) << 11) + s0 + sc;
        *(ushort8*)dst       = o0;
        *(ushort8*)(dst + 8) = o1;
    }
}

// ---------------------------------------------------------------------------
// attn2: swapped-QK^T fused attention. One barrier per kt; counted vmcnt so
// the stage loads (oldest VMEM) are waited without draining attn stores
// (youngest). Lane (fr,fg): q=fr, k=16n+fg*4+r. LDS 48 KB -> 3 blocks/CU.
// ---------------------------------------------------------------------------
#define STAGE_K(ktv, bufsel)                                                     \
    {                                                                            \
        const int kti_ = (ktv) & 15;                                             \
        _Pragma("unroll")                                                        \
        for (int c_ = 0; c_ < 4; ++c_) {                                         \
            const int rb_ = (w << 5) + (c_ << 3);                                \
            const int rl_ = rb_ + (lane >> 3);                                   \
            const unsigned short* ks_ = Kb + (((size_t)((kti_ << 7) + rl_) * 2 + b) << 10) \
                + (h << 6) + (((lane & 7) ^ (rl_ & 7)) << 3);                    \
            GLOAD_LDS16(ks_, &Ks[bufsel][rb_ * 64]);                             \
        }                                                                        \
    }

__global__ __launch_bounds__(256) void attn2(
    const unsigned short* __restrict__ Qb, const unsigned short* __restrict__ Kb,
    const unsigned short* __restrict__ Vt, float* __restrict__ attn_out,
    unsigned short* __restrict__ Hb)
{
    __shared__ unsigned short Ks[2][128 * 64];   // 32 KB double-buffered K
    __shared__ unsigned short Pl[4][16 * 128];   // 16 KB, per-wave 16x128 bf16

    const int flat = blockIdx.x + (blockIdx.y << 4) + (blockIdx.z << 8);
    const int nf = (flat & 7) * 64 + (flat >> 3);
    const int qblk = nf & 15, h = (nf >> 4) & 15, b = nf >> 8;

    const int t = threadIdx.x, lane = t & 63, w = t >> 6;
    const int fr = lane & 15, fg = lane >> 4;
    const int fg4 = fg << 2, fg16 = fg << 4;
    const int qbase = qblk * 128 + w * 32;
    const float c_exp = 0.18033688011112042f;    // log2(e)/8

    bf16x8 qf[2][2];
    #pragma unroll
    for (int mi = 0; mi < 2; ++mi) {
        const int q = qbase + mi * 16 + fr;
        const unsigned short* qp = Qb + (((size_t)q * 2 + b) << 10) + (h << 6);
        qf[mi][0] = *(const bf16x8*)(qp + (fg << 3));
        qf[mi][1] = *(const bf16x8*)(qp + 32 + (fg << 3));
    }

    char* Plc = (char*)&Pl[w][0];
    float lsum[2] = {0.f, 0.f};

    // ---------------- pass 1: row sums (stage is the only VMEM) ----------------
    STAGE_K(0, 0);
    WAIT_VMCNT(0);
    SBAR();
    for (int kt = 0; kt < 16; ++kt) {
        STAGE_K(kt + 1, (kt + 1) & 1);
        SCHED_FENCE();

        const char* Kc = (const char*)Ks[kt & 1];
        f32x4 s_[2][8] = {};
        __builtin_amdgcn_s_setprio(1);
        #pragma unroll
        for (int n = 0; n < 8; ++n) {
            const int row = (n << 4) + fr;
            const int rx = (row & 7) << 4;
            #pragma unroll
            for (int kk = 0; kk < 2; ++kk) {
                bf16x8 kf = *(const bf16x8*)(Kc + (row << 7) + (((kk << 6) | fg16) ^ rx));
                s_[0][n] = MFMA16(kf, qf[0][kk], s_[0][n]);
                s_[1][n] = MFMA16(kf, qf[1][kk], s_[1][n]);
            }
        }
        __builtin_amdgcn_s_setprio(0);

        #pragma unroll
        for (int mi = 0; mi < 2; ++mi) {
            float a = 0.f;
            #pragma unroll
            for (int n = 0; n < 8; ++n)
                #pragma unroll
                for (int r = 0; r < 4; ++r)
                    a += exp2f(s_[mi][n][r] * c_exp);
            lsum[mi] += a;
        }

        WAIT_VMCNT(0);      // only the 4 stage loads are outstanding
        SBAR();
    }

    float li[2];
    #pragma unroll
    for (int mi = 0; mi < 2; ++mi) {
        float v = lsum[mi];
        v += __shfl_xor(v, 16);
        v += __shfl_xor(v, 32);
        li[mi] = -__log2f(v);                    // fold 1/sum into exponent
    }

    f32x4 oacc[2][4] = {};
    float* attnB = attn_out + ((size_t)((b << 4) + h) << 22);
    const size_t vhead = (size_t)((b << 4) + h) << 6;

    // ---------------- pass 2 ----------------
    // pass 1's final STAGE_K staged tile 0 into Ks[0] (drained by final wait).
    for (int kt = 0; kt < 16; ++kt) {
        STAGE_K(kt + 1, (kt + 1) & 1);           // 4 loads, oldest VMEM this iter
        SCHED_FENCE();                           // pin: nothing hoists above stage

        const char* Kc = (const char*)Ks[kt & 1];
        f32x4 s_[2][8] = {};
        __builtin_amdgcn_s_setprio(1);
        #pragma unroll
        for (int n = 0; n < 8; ++n) {
            const int row = (n << 4) + fr;
            const int rx = (row & 7) << 4;
            #pragma unroll
            for (int kk = 0; kk < 2; ++kk) {
                bf16x8 kf = *(const bf16x8*)(Kc + (row << 7) + (((kk << 6) | fg16) ^ rx));
                s_[0][n] = MFMA16(kf, qf[0][kk], s_[0][n]);
                s_[1][n] = MFMA16(kf, qf[1][kk], s_[1][n]);
            }
        }
        __builtin_amdgcn_s_setprio(0);

        const int rxl = (fr & 7) << 4;
        #pragma unroll
        for (int mi = 0; mi < 2; ++mi) {
            // p = 2^(s*c + log2(inv)); attn store (8x dwordx4); packed Pl write
            float* ab = attnB + ((size_t)(qbase + (mi << 4) + fr) << 11) + (kt << 7) + fg4;
            #pragma unroll
            for (int n = 0; n < 8; ++n) {
                f32x4 p;
                #pragma unroll
                for (int r = 0; r < 4; ++r)
                    p[r] = exp2f(__builtin_fmaf(s_[mi][n][r], c_exp, li[mi]));
                *(f32x4*)(ab + (n << 4)) = p;
                uint2 pk;
                pk.x = pack_bf16_pair(p[0], p[1]);
                pk.y = pack_bf16_pair(p[2], p[3]);
                *(uint2*)(Plc + (fr << 8) + (((n << 5) | (fg << 3)) ^ rxl)) = pk;
            }
            WAIT_LGKM0();
            SCHED_FENCE();                        // rule #18: no MFMA hoist past wait

            // PV (this mi): oacc[mi] += P(16x128) @ V(128x64), 16 Vt loads
            __builtin_amdgcn_s_setprio(1);
            #pragma unroll
            for (int kk2 = 0; kk2 < 4; ++kk2) {
                bf16x8 pa = *(const bf16x8*)(Plc + (fr << 8) + (((kk2 << 6) | fg16) ^ rxl));
                #pragma unroll
                for (int n2 = 0; n2 < 4; ++n2) {
                    bf16x8 vf = *(const bf16x8*)(Vt + ((vhead + (n2 << 4) + fr) << 11)
                                                 + (kt << 7) + (kk2 << 5) + (fg << 3));
                    oacc[mi][n2] = MFMA16(pa, vf, oacc[mi][n2]);
                }
            }
            __builtin_amdgcn_s_setprio(0);
        }

        // younger-than-stage VMEM: 2*(8 stores + 16 Vt loads) = 48.
        // vmcnt(48): retires exactly the 4 stage loads (in-order), leaves the
        // store burst in flight for a full extra iteration.
        WAIT_VMCNT(48);
        SBAR();
    }

    #pragma unroll
    for (int mi = 0; mi < 2; ++mi)
        #pragma unroll
        for (int n2 = 0; n2 < 4; ++n2)
            #pragma unroll
            for (int r = 0; r < 4; ++r) {
                const int q = qbase + (mi << 4) + fg4 + r;
                *(__bf16*)&Hb[(((size_t)q * 2 + b) << 10) + (h << 6) + (n2 << 4) + fr] =
                    (__bf16)oacc[mi][n2][r];
            }
}

// ---------------------------------------------------------------------------
// out_proj: out = H @ Wob^T + bo (fp32), double-buffered BK=32.
// ---------------------------------------------------------------------------
__global__ __launch_bounds__(256) void out_proj(
    const unsigned short* __restrict__ Hb, const unsigned short* __restrict__ Wob,
    const float* __restrict__ bo, float* __restrict__ out)
{
    __shared__ unsigned short As[2][128 * 32];
    __shared__ unsigned short Bs[2][128 * 32];

    const int t = threadIdx.x, lane = t & 63, w = t >> 6;
    const int wm = w >> 1, wn = w & 1;
    const int bm = blockIdx.x * 128, bn = blockIdx.y * 128;
    const int fr = lane & 15, fg = lane >> 4;

    const unsigned short* Ap = Hb + (size_t)bm * HID;
    const unsigned short* Bp = Wob + (size_t)bn * HID;

    f32x4 acc[4][4] = {};
    GEMM_BODY(Ap, Bp)

    #pragma unroll
    for (int n = 0; n < 4; ++n) {
        const int gc = bn + wn * 64 + n * 16 + fr;
        const float bb = bo[gc];
        #pragma unroll
        for (int m = 0; m < 4; ++m)
            #pragma unroll
            for (int r = 0; r < 4; ++r) {
                const int gr = bm + wm * 64 + m * 16 + fg * 4 + r;
                out[(size_t)gr * HID + gc] = acc[m][n][r] + bb;
            }
    }
}

// ---------------------------------------------------------------------------
extern "C" void kernel_launch(void* const* d_in, const int* in_sizes, int n_in,
                              void* d_out, int out_size, void* d_ws, size_t ws_size,
                              hipStream_t stream)
{
    (void)in_sizes; (void)n_in; (void)out_size;

    const float* query = (const float*)d_in[0];
    const float* key   = (const float*)d_in[1];
    const float* value = (const float*)d_in[2];
    const float* bq    = (const float*)d_in[4];
    const float* bk    = (const float*)d_in[6];
    const float* bv    = (const float*)d_in[8];
    const float* Wo    = (const float*)d_in[9];
    const float* bo    = (const float*)d_in[10];

    float* out0 = (float*)d_out;
    float* attn = out0 + (size_t)MROWS * HID;

    if (ws_size < (size_t)32 * 1024 * 1024) return;
    const size_t nbuf = (size_t)MROWS * HID;            // 4M bf16 = 8MB
    unsigned short* Qb = (unsigned short*)d_ws;         // [0, 8MB)
    unsigned short* Kb = Qb + nbuf;                     // [8, 16MB)
    unsigned short* Vb = Kb + nbuf;                     // [16, 24MB) -> Hb after vtrans
    unsigned short* Vt = Vb + nbuf;                     // [24, 32MB)
    unsigned short* Hb = Vb;
    unsigned short* Wob = Qb;                           // Qb dead after attn2

    unsigned short* Sc = (unsigned short*)attn;         // scratch inside attn area (30MB)

    conv6<<<dim3(2048, 6), 256, 0, stream>>>(query, key, value,
                                             (const float*)d_in[3], (const float*)d_in[5],
                                             (const float*)d_in[7], Sc);
    qkv_gemm<<<dim3(32, 8, 3), 256, 0, stream>>>(Sc, bq, bk, bv, Qb, Kb, Vb);
    vtrans<<<dim3(32, NHEAD, NBATCH), 256, 0, stream>>>(Vb, Vt);
    attn2<<<dim3(16, NHEAD, NBATCH), 256, 0, stream>>>(Qb, Kb, Vt, attn, Hb);
    wconv<<<dim3(512), 256, 0, stream>>>(Wo, Wob);
    out_proj<<<dim3(32, 8), 256, 0, stream>>>(Hb, Wob, bo, out0);
}

// Round 7
// 338.819 us; speedup vs baseline: 1.1777x; 1.1357x over previous
//
#include <hip/hip_runtime.h>
#include <hip/hip_bf16.h>
#include <cstdint>
#include <cstddef>

#define SEQLEN 2048
#define NBATCH 2
#define NHEAD  16
#define HDIM   64
#define HID    1024
#define MROWS  4096   // row r = s*2 + b

typedef __bf16 bf16x8 __attribute__((ext_vector_type(8)));
typedef float f32x4 __attribute__((ext_vector_type(4)));
typedef unsigned short ushort8 __attribute__((ext_vector_type(8)));

#define MFMA16(a, b, c) __builtin_amdgcn_mfma_f32_16x16x32_bf16((a), (b), (c), 0, 0, 0)

#define GLOAD_LDS16(g, l)                                                        \
    __builtin_amdgcn_global_load_lds(                                            \
        (const __attribute__((address_space(1))) void*)(g),                      \
        (__attribute__((address_space(3))) void*)(l), 16, 0, 0)

#define SBAR() __builtin_amdgcn_s_barrier()
#define SCHED_FENCE() __builtin_amdgcn_sched_barrier(0)
#define WAIT_VMCNT(n) asm volatile("s_waitcnt vmcnt(" #n ")" ::: "memory")

static __device__ __forceinline__ unsigned int pack_bf16_pair(float lo, float hi) {
    unsigned short a = __builtin_bit_cast(unsigned short, (__bf16)lo);
    unsigned short b = __builtin_bit_cast(unsigned short, (__bf16)hi);
    return ((unsigned int)b << 16) | a;
}

// ---------------------------------------------------------------------------
// conv6: fp32 -> bf16 for {query,key,value,Wq,Wk,Wv} into scratch (attn area)
// ---------------------------------------------------------------------------
__global__ __launch_bounds__(256) void conv6(
    const float* __restrict__ s0, const float* __restrict__ s1, const float* __restrict__ s2,
    const float* __restrict__ s3, const float* __restrict__ s4, const float* __restrict__ s5,
    unsigned short* __restrict__ Sc)
{
    const int y = blockIdx.y;
    const float* src = (y == 0) ? s0 : (y == 1) ? s1 : (y == 2) ? s2
                     : (y == 3) ? s3 : (y == 4) ? s4 : s5;
    const size_t M1 = 1u << 20;
    unsigned short* dst = (y < 3) ? (Sc + (size_t)y * 4 * M1) : (Sc + 12 * M1 + (size_t)(y - 3) * M1);
    const size_t n = (y < 3) ? 4 * M1 : M1;

    const size_t i = ((size_t)blockIdx.x * 256 + threadIdx.x) * 8;
    if (i >= n) return;
    float4 f0 = *(const float4*)(src + i);
    float4 f1 = *(const float4*)(src + i + 4);
    ushort8 o;
    o[0] = __builtin_bit_cast(unsigned short, (__bf16)f0.x);
    o[1] = __builtin_bit_cast(unsigned short, (__bf16)f0.y);
    o[2] = __builtin_bit_cast(unsigned short, (__bf16)f0.z);
    o[3] = __builtin_bit_cast(unsigned short, (__bf16)f0.w);
    o[4] = __builtin_bit_cast(unsigned short, (__bf16)f1.x);
    o[5] = __builtin_bit_cast(unsigned short, (__bf16)f1.y);
    o[6] = __builtin_bit_cast(unsigned short, (__bf16)f1.z);
    o[7] = __builtin_bit_cast(unsigned short, (__bf16)f1.w);
    *(ushort8*)(dst + i) = o;
}

__global__ __launch_bounds__(256) void wconv(
    const float* __restrict__ Wo, unsigned short* __restrict__ Wob)
{
    const size_t i = ((size_t)blockIdx.x * 256 + threadIdx.x) * 8;
    float4 f0 = *(const float4*)(Wo + i);
    float4 f1 = *(const float4*)(Wo + i + 4);
    ushort8 o;
    o[0] = __builtin_bit_cast(unsigned short, (__bf16)f0.x);
    o[1] = __builtin_bit_cast(unsigned short, (__bf16)f0.y);
    o[2] = __builtin_bit_cast(unsigned short, (__bf16)f0.z);
    o[3] = __builtin_bit_cast(unsigned short, (__bf16)f0.w);
    o[4] = __builtin_bit_cast(unsigned short, (__bf16)f1.x);
    o[5] = __builtin_bit_cast(unsigned short, (__bf16)f1.y);
    o[6] = __builtin_bit_cast(unsigned short, (__bf16)f1.z);
    o[7] = __builtin_bit_cast(unsigned short, (__bf16)f1.w);
    *(ushort8*)(Wob + i) = o;
}

// ---------------------------------------------------------------------------
// Double-buffered bf16 GEMM (BK=32), R4-proven: per-iter
// {SBAR; stage(it+1); vmcnt(8) [waits prev tile only]; SBAR; compute(it)}.
// ---------------------------------------------------------------------------
#define GSTAGE32(DSTARR, SRCP, k0v)                                              \
    _Pragma("unroll")                                                            \
    for (int c_ = 0; c_ < 2; ++c_) {                                             \
        const int row_ = (c_ << 6) + (threadIdx.x >> 2);                         \
        const unsigned short* gs_ = (SRCP) + (size_t)row_ * HID + (k0v)          \
            + ((((int)threadIdx.x & 3) ^ ((row_ >> 1) & 3)) << 3);               \
        GLOAD_LDS16(gs_, &(DSTARR)[((c_ << 6) + (((int)threadIdx.x >> 6) << 4)) * 32]); \
    }

#define GEMM_BODY(ApT, BpT)                                                      \
    GSTAGE32(As[0], ApT, 0);                                                     \
    GSTAGE32(Bs[0], BpT, 0);                                                     \
    for (int it = 0; it < 32; ++it) {                                            \
        SBAR();                                                                  \
        const int k1 = ((it + 1) & 31) << 5;                                     \
        GSTAGE32(As[(it + 1) & 1], ApT, k1);                                     \
        GSTAGE32(Bs[(it + 1) & 1], BpT, k1);                                     \
        WAIT_VMCNT(8);                                                           \
        SBAR();                                                                  \
        SCHED_FENCE();                                                           \
        const char* Ac = (const char*)As[it & 1];                                \
        const char* Bc = (const char*)Bs[it & 1];                                \
        bf16x8 a_h[4], b_h[4];                                                   \
        _Pragma("unroll")                                                        \
        for (int m = 0; m < 4; ++m) {                                            \
            const int row = wm * 64 + m * 16 + fr;                               \
            a_h[m] = *(const bf16x8*)(Ac + (row << 6) + ((fg ^ ((row >> 1) & 3)) << 4)); \
        }                                                                        \
        _Pragma("unroll")                                                        \
        for (int n = 0; n < 4; ++n) {                                            \
            const int row = wn * 64 + n * 16 + fr;                               \
            b_h[n] = *(const bf16x8*)(Bc + (row << 6) + ((fg ^ ((row >> 1) & 3)) << 4)); \
        }                                                                        \
        __builtin_amdgcn_s_setprio(1);                                           \
        _Pragma("unroll")                                                        \
        for (int m = 0; m < 4; ++m)                                              \
            _Pragma("unroll")                                                    \
            for (int n = 0; n < 4; ++n)                                          \
                acc[m][n] = MFMA16(a_h[m], b_h[n], acc[m][n]);                   \
        __builtin_amdgcn_s_setprio(0);                                           \
    }

__global__ __launch_bounds__(256) void qkv_gemm(
    const unsigned short* __restrict__ Sc,
    const float* __restrict__ bq, const float* __restrict__ bk, const float* __restrict__ bv,
    unsigned short* __restrict__ Qb, unsigned short* __restrict__ Kb, unsigned short* __restrict__ Vb)
{
    const int z = blockIdx.z;
    const size_t M1 = 1u << 20;
    const unsigned short* A = Sc + (size_t)z * 4 * M1;
    const unsigned short* B = Sc + 12 * M1 + (size_t)z * M1;
    const float* bias = (z == 0) ? bq : (z == 1) ? bk : bv;
    unsigned short* dst = (z == 0) ? Qb : (z == 1) ? Kb : Vb;

    __shared__ unsigned short As[2][128 * 32];
    __shared__ unsigned short Bs[2][128 * 32];

    const int t = threadIdx.x, lane = t & 63, w = t >> 6;
    const int wm = w >> 1, wn = w & 1;
    const int bm = blockIdx.x * 128, bn = blockIdx.y * 128;
    const int fr = lane & 15, fg = lane >> 4;

    const unsigned short* Ap = A + (size_t)bm * HID;
    const unsigned short* Bp = B + (size_t)bn * HID;

    f32x4 acc[4][4] = {};
    GEMM_BODY(Ap, Bp)

    #pragma unroll
    for (int n = 0; n < 4; ++n) {
        const int gc = bn + wn * 64 + n * 16 + fr;
        const float bb = bias[gc];
        #pragma unroll
        for (int m = 0; m < 4; ++m)
            #pragma unroll
            for (int r = 0; r < 4; ++r) {
                const int gr = bm + wm * 64 + m * 16 + fg * 4 + r;
                *(__bf16*)&dst[(size_t)gr * HID + gc] = (__bf16)(acc[m][n][r] + bb);
            }
    }
}

// ---------------------------------------------------------------------------
// vtrans: LDS-tiled transpose Vb [s2][h*64+d] -> Vt [b][h][d][s]
// ---------------------------------------------------------------------------
__global__ __launch_bounds__(256) void vtrans(
    const unsigned short* __restrict__ Vb, unsigned short* __restrict__ Vt)
{
    __shared__ unsigned short T[64][66];
    const int t = threadIdx.x;
    const int s0 = blockIdx.x * 64, h = blockIdx.y, b = blockIdx.z;

    {
        const int s_l = t >> 2, d0 = (t & 3) * 16;
        const unsigned short* src = Vb + (((size_t)(s0 + s_l) * 2 + b) << 10) + (h << 6) + d0;
        *(ushort8*)&T[s_l][d0]     = *(const ushort8*)src;
        *(ushort8*)&T[s_l][d0 + 8] = *(const ushort8*)(src + 8);
    }
    __syncthreads();
    {
        const int d_l = t >> 2, sc = (t & 3) * 16;
        ushort8 o0, o1;
        #pragma unroll
        for (int j = 0; j < 8; ++j) { o0[j] = T[sc + j][d_l]; o1[j] = T[sc + 8 + j][d_l]; }
        unsigned short* dst = Vt + (((size_t)((b << 4) + h) * 64 + d_l) << 11) + s0 + sc;
        *(ushort8*)dst       = o0;
        *(ushort8*)(dst + 8) = o1;
    }
}

// ---------------------------------------------------------------------------
// attn2: swapped-QK^T fused attention. 64 q-rows/block (4 waves x 16 q) ->
// 1024 blocks = 4/CU (TLP hides barrier drains). Single-buffered K staging,
// plain __syncthreads, no manual waits, no NT stores. LDS 32 KB.
// Lane (fr,fg): q=fr, k=16n+fg*4+r.
// ---------------------------------------------------------------------------
#define STAGE_K1(ktv)                                                            \
    {                                                                            \
        const int kti_ = (ktv);                                                  \
        _Pragma("unroll")                                                        \
        for (int c_ = 0; c_ < 4; ++c_) {                                         \
            const int rb_ = (w << 5) + (c_ << 3);                                \
            const int rl_ = rb_ + (lane >> 3);                                   \
            const unsigned short* ks_ = Kb + (((size_t)((kti_ << 7) + rl_) * 2 + b) << 10) \
                + (h << 6) + (((lane & 7) ^ (rl_ & 7)) << 3);                    \
            GLOAD_LDS16(ks_, &Ks[rb_ * 64]);                                     \
        }                                                                        \
    }

__global__ __launch_bounds__(256) void attn2(
    const unsigned short* __restrict__ Qb, const unsigned short* __restrict__ Kb,
    const unsigned short* __restrict__ Vt, float* __restrict__ attn_out,
    unsigned short* __restrict__ Hb)
{
    __shared__ unsigned short Ks[128 * 64];      // 16 KB single buffer
    __shared__ unsigned short Pl[4][16 * 128];   // 16 KB, per-wave 16x128 bf16

    // XCD swizzle: 1024 blocks, 128 consecutive per XCD (4 heads x 32 qblk)
    const int flat = blockIdx.x + (blockIdx.y << 5) + (blockIdx.z << 9);
    const int nf = (flat & 7) * 128 + (flat >> 3);
    const int qblk = nf & 31, h = (nf >> 5) & 15, b = nf >> 9;

    const int t = threadIdx.x, lane = t & 63, w = t >> 6;
    const int fr = lane & 15, fg = lane >> 4;
    const int fg4 = fg << 2, fg16 = fg << 4;
    const int qbase = qblk * 64 + w * 16;
    const float c_exp = 0.18033688011112042f;    // log2(e)/8

    bf16x8 qf[2];
    {
        const int q = qbase + fr;
        const unsigned short* qp = Qb + (((size_t)q * 2 + b) << 10) + (h << 6);
        qf[0] = *(const bf16x8*)(qp + (fg << 3));
        qf[1] = *(const bf16x8*)(qp + 32 + (fg << 3));
    }

    char* Plc = (char*)&Pl[w][0];
    float lsum = 0.f;

    // ---------------- pass 1: row sums ----------------
    for (int kt = 0; kt < 16; ++kt) {
        __syncthreads();
        STAGE_K1(kt);
        __syncthreads();

        const char* Kc = (const char*)Ks;
        f32x4 s_[8] = {};
        __builtin_amdgcn_s_setprio(1);
        #pragma unroll
        for (int n = 0; n < 8; ++n) {
            const int row = (n << 4) + fr;
            const int rx = (row & 7) << 4;
            #pragma unroll
            for (int kk = 0; kk < 2; ++kk) {
                bf16x8 kf = *(const bf16x8*)(Kc + (row << 7) + (((kk << 6) | fg16) ^ rx));
                s_[n] = MFMA16(kf, qf[kk], s_[n]);
            }
        }
        __builtin_amdgcn_s_setprio(0);

        float a = 0.f;
        #pragma unroll
        for (int n = 0; n < 8; ++n)
            #pragma unroll
            for (int r = 0; r < 4; ++r)
                a += exp2f(s_[n][r] * c_exp);
        lsum += a;
    }

    float li;
    {
        float v = lsum;
        v += __shfl_xor(v, 16);
        v += __shfl_xor(v, 32);
        li = -__log2f(v);                        // fold 1/sum into exponent
    }

    f32x4 oacc[4] = {};
    float* attnB = attn_out + ((size_t)((b << 4) + h) << 22);
    const size_t vhead = (size_t)((b << 4) + h) << 6;
    const int rxl = (fr & 7) << 4;

    // ---------------- pass 2 ----------------
    for (int kt = 0; kt < 16; ++kt) {
        __syncthreads();
        STAGE_K1(kt);
        __syncthreads();

        const char* Kc = (const char*)Ks;
        f32x4 s_[8] = {};
        __builtin_amdgcn_s_setprio(1);
        #pragma unroll
        for (int n = 0; n < 8; ++n) {
            const int row = (n << 4) + fr;
            const int rx = (row & 7) << 4;
            #pragma unroll
            for (int kk = 0; kk < 2; ++kk) {
                bf16x8 kf = *(const bf16x8*)(Kc + (row << 7) + (((kk << 6) | fg16) ^ rx));
                s_[n] = MFMA16(kf, qf[kk], s_[n]);
            }
        }
        __builtin_amdgcn_s_setprio(0);

        // p = 2^(s*c + log2(inv)); plain dwordx4 attn store; packed b64 -> Pl
        float* ab = attnB + ((size_t)(qbase + fr) << 11) + (kt << 7) + fg4;
        #pragma unroll
        for (int n = 0; n < 8; ++n) {
            f32x4 p;
            #pragma unroll
            for (int r = 0; r < 4; ++r)
                p[r] = exp2f(__builtin_fmaf(s_[n][r], c_exp, li));
            *(f32x4*)(ab + (n << 4)) = p;
            uint2 pk;
            pk.x = pack_bf16_pair(p[0], p[1]);
            pk.y = pack_bf16_pair(p[2], p[3]);
            *(uint2*)(Plc + (fr << 8) + (((n << 5) | (fg << 3)) ^ rxl)) = pk;
        }

        // PV: oacc += P(16x128) @ V(128x64)  (compiler orders Pl RAW via lgkm)
        __builtin_amdgcn_s_setprio(1);
        #pragma unroll
        for (int kk2 = 0; kk2 < 4; ++kk2) {
            bf16x8 pa = *(const bf16x8*)(Plc + (fr << 8) + (((kk2 << 6) | fg16) ^ rxl));
            #pragma unroll
            for (int n2 = 0; n2 < 4; ++n2) {
                bf16x8 vf = *(const bf16x8*)(Vt + ((vhead + (n2 << 4) + fr) << 11)
                                             + (kt << 7) + (kk2 << 5) + (fg << 3));
                oacc[n2] = MFMA16(pa, vf, oacc[n2]);
            }
        }
        __builtin_amdgcn_s_setprio(0);
    }

    #pragma unroll
    for (int n2 = 0; n2 < 4; ++n2)
        #pragma unroll
        for (int r = 0; r < 4; ++r) {
            const int q = qbase + fg4 + r;
            *(__bf16*)&Hb[(((size_t)q * 2 + b) << 10) + (h << 6) + (n2 << 4) + fr] =
                (__bf16)oacc[n2][r];
        }
}

// ---------------------------------------------------------------------------
// out_proj: out = H @ Wob^T + bo (fp32), double-buffered BK=32.
// ---------------------------------------------------------------------------
__global__ __launch_bounds__(256) void out_proj(
    const unsigned short* __restrict__ Hb, const unsigned short* __restrict__ Wob,
    const float* __restrict__ bo, float* __restrict__ out)
{
    __shared__ unsigned short As[2][128 * 32];
    __shared__ unsigned short Bs[2][128 * 32];

    const int t = threadIdx.x, lane = t & 63, w = t >> 6;
    const int wm = w >> 1, wn = w & 1;
    const int bm = blockIdx.x * 128, bn = blockIdx.y * 128;
    const int fr = lane & 15, fg = lane >> 4;

    const unsigned short* Ap = Hb + (size_t)bm * HID;
    const unsigned short* Bp = Wob + (size_t)bn * HID;

    f32x4 acc[4][4] = {};
    GEMM_BODY(Ap, Bp)

    #pragma unroll
    for (int n = 0; n < 4; ++n) {
        const int gc = bn + wn * 64 + n * 16 + fr;
        const float bb = bo[gc];
        #pragma unroll
        for (int m = 0; m < 4; ++m)
            #pragma unroll
            for (int r = 0; r < 4; ++r) {
                const int gr = bm + wm * 64 + m * 16 + fg * 4 + r;
                out[(size_t)gr * HID + gc] = acc[m][n][r] + bb;
            }
    }
}

// ---------------------------------------------------------------------------
extern "C" void kernel_launch(void* const* d_in, const int* in_sizes, int n_in,
                              void* d_out, int out_size, void* d_ws, size_t ws_size,
                              hipStream_t stream)
{
    (void)in_sizes; (void)n_in; (void)out_size;

    const float* query = (const float*)d_in[0];
    const float* key   = (const float*)d_in[1];
    const float* value = (const float*)d_in[2];
    const float* bq    = (const float*)d_in[4];
    const float* bk    = (const float*)d_in[6];
    const float* bv    = (const float*)d_in[8];
    const float* Wo    = (const float*)d_in[9];
    const float* bo    = (const float*)d_in[10];

    float* out0 = (float*)d_out;
    float* attn = out0 + (size_t)MROWS * HID;

    if (ws_size < (size_t)32 * 1024 * 1024) return;
    const size_t nbuf = (size_t)MROWS * HID;            // 4M bf16 = 8MB
    unsigned short* Qb = (unsigned short*)d_ws;         // [0, 8MB)
    unsigned short* Kb = Qb + nbuf;                     // [8, 16MB)
    unsigned short* Vb = Kb + nbuf;                     // [16, 24MB) -> Hb after vtrans
    unsigned short* Vt = Vb + nbuf;                     // [24, 32MB)
    unsigned short* Hb = Vb;
    unsigned short* Wob = Qb;                           // Qb dead after attn2

    unsigned short* Sc = (unsigned short*)attn;         // scratch inside attn area (30MB)

    conv6<<<dim3(2048, 6), 256, 0, stream>>>(query, key, value,
                                             (const float*)d_in[3], (const float*)d_in[5],
                                             (const float*)d_in[7], Sc);
    qkv_gemm<<<dim3(32, 8, 3), 256, 0, stream>>>(Sc, bq, bk, bv, Qb, Kb, Vb);
    vtrans<<<dim3(32, NHEAD, NBATCH), 256, 0, stream>>>(Vb, Vt);
    attn2<<<dim3(32, NHEAD, NBATCH), 256, 0, stream>>>(Qb, Kb, Vt, attn, Hb);
    wconv<<<dim3(512), 256, 0, stream>>>(Wo, Wob);
    out_proj<<<dim3(32, 8), 256, 0, stream>>>(Hb, Wob, bo, out0);
}